// Round 1
// baseline (257.317 us; speedup 1.0000x reference)
//
#include <hip/hip_runtime.h>

#define BATCH 4
#define CCH   512
#define NN    4096
#define MIDD  64

typedef unsigned short u16;
typedef unsigned int   u32;
typedef short s8v  __attribute__((ext_vector_type(8)));
typedef float f16v __attribute__((ext_vector_type(16)));

__device__ __forceinline__ u16 f2bf(float f) {
  u32 u = __float_as_uint(f);
  u += 0x7fffu + ((u >> 16) & 1u);   // RTNE
  return (u16)(u >> 16);
}

// async global->LDS DMA, 16B per lane; dest = wave-uniform base + lane*16
__device__ __forceinline__ void g2lds16(const u16* g, u16* l) {
  __builtin_amdgcn_global_load_lds(
      (const __attribute__((address_space(1))) u32*)(const void*)g,
      (__attribute__((address_space(3))) u32*)(void*)l, 16, 0, 0);
}

// s_waitcnt imm (gfx9): vmcnt [3:0]+[15:14], expcnt [6:4]=7, lgkmcnt [11:8]
#define S_WAITCNT(vm, lgkm) \
  __builtin_amdgcn_s_waitcnt(((vm) & 15) | (((vm) >> 4) << 14) | (0x7 << 4) | ((lgkm) << 8))

// ---------------------------------------------------------------------------
// prep_w: Wb[640][512] bf16 = [Wq; Wk; Wv] fp32, converted once.
// ---------------------------------------------------------------------------
__global__ __launch_bounds__(256) void prep_w(
    const float* __restrict__ Wq, const float* __restrict__ Wk,
    const float* __restrict__ Wv, u16* __restrict__ Wb)
{
  int e = (blockIdx.x * 256 + threadIdx.x) * 8;
  const float* src;
  if (e < 64 * 512)       src = Wq + e;
  else if (e < 128 * 512) src = Wk + (e - 64 * 512);
  else                    src = Wv + (e - 128 * 512);
  float4 v0 = *(const float4*)src;
  float4 v1 = *(const float4*)(src + 4);
  uint4 p;
  p.x = (u32)f2bf(v0.x) | ((u32)f2bf(v0.y) << 16);
  p.y = (u32)f2bf(v0.z) | ((u32)f2bf(v0.w) << 16);
  p.z = (u32)f2bf(v1.x) | ((u32)f2bf(v1.y) << 16);
  p.w = (u32)f2bf(v1.z) | ((u32)f2bf(v1.w) << 16);
  *(uint4*)(Wb + e) = p;
}

// ---------------------------------------------------------------------------
// transpose_cast: xbT[b][n][c] (bf16) = x[b][c][n] (fp32). 64x64 tiles.
// ---------------------------------------------------------------------------
__global__ __launch_bounds__(256) void transpose_cast(
    const float* __restrict__ x, u16* __restrict__ xbT)
{
  const int b  = blockIdx.z;
  const int c0 = blockIdx.y * 64;
  const int n0 = blockIdx.x * 64;
  const int t  = threadIdx.x;
  __shared__ float ts[64 * 65];

  #pragma unroll
  for (int k = 0; k < 4; k++) {
    int idx = t + 256 * k;
    int cc = idx >> 4, n4 = idx & 15;
    float4 v = *(const float4*)&x[((size_t)(b * CCH + c0 + cc)) * NN + n0 + n4 * 4];
    float* p = &ts[cc * 65 + n4 * 4];
    p[0] = v.x; p[1] = v.y; p[2] = v.z; p[3] = v.w;
  }
  __syncthreads();

  const int n = t >> 2, cb = (t & 3) * 16;
  u16 tmp[16];
  #pragma unroll
  for (int j = 0; j < 16; j++) tmp[j] = f2bf(ts[(cb + j) * 65 + n]);
  u16* dst = &xbT[((size_t)b * NN + n0 + n) * CCH + c0 + cb];
  *(uint4*)&dst[0] = *(uint4*)&tmp[0];
  *(uint4*)&dst[8] = *(uint4*)&tmp[8];
}

// ---------------------------------------------------------------------------
// proj_gemm v3: all-DMA staging, BK=32, double-buffered ws+xs, raw barriers
// with vmcnt(5) (chunk i+1 stays in flight across the barrier).
// LDS rows 32 u16 = 64B = 4 16B-blocks; phys block p holds logical p^(row&3).
// Block: 64m x 256n; wave w: m-subs{0,1} x n-subs{2w,2w+1}. 40 KB LDS.
// ---------------------------------------------------------------------------
__global__ __launch_bounds__(256, 2) void proj_gemm(
    const u16* __restrict__ xbT, const u16* __restrict__ Wb,
    const float* __restrict__ bq, const float* __restrict__ bk,
    const float* __restrict__ bv,
    u16* __restrict__ qT, u16* __restrict__ kT, u16* __restrict__ vT)
{
  const int b  = blockIdx.z;
  const int mt = blockIdx.y;
  const int n0 = blockIdx.x * 256;
  const int t  = threadIdx.x;
  const int ln = t & 31, hi = (t & 63) >> 5, w = t >> 6;
  const int l  = t & 63;
  const int l2 = l & 3, lr = l >> 2;        // DMA: phys block, row-in-group
  const int swc = (l2 ^ (lr & 3)) * 8;      // content col offset (u16)

  const int mrow0 = (mt < 8) ? (128 + mt * 64) : ((mt == 8) ? 0 : 64);
  const float* bias = (mt < 8) ? (bv + mt * 64) : ((mt == 8) ? bq : bk);

  __shared__ u16 ws[2][64 * 32];    // W chunk [m][c32], swizzled
  __shared__ u16 xs[2][256 * 32];   // x chunk [n][c32], swizzled

  // DMA sources (chunk col offset added per iter)
  const u16* xsrc = xbT + ((size_t)b * NN + n0 + w * 64 + lr) * CCH + swc;
  const u16* wsrc = Wb + (size_t)(mrow0 + w * 16 + lr) * 512 + swc;

  f16v acc[4];
  #pragma unroll
  for (int i = 0; i < 4; i++)
    #pragma unroll
    for (int r = 0; r < 16; r++) acc[i][r] = 0.f;

  // prologue: issue chunk 0 into buf 0
  #pragma unroll
  for (int i = 0; i < 4; i++)
    g2lds16(xsrc + (size_t)(16 * i) * CCH, &xs[0][(w * 64 + i * 16) * 32]);
  g2lds16(wsrc, &ws[0][w * 16 * 32]);

  for (int it = 0; it < 16; it++) {
    const int cur = it & 1, nxt = cur ^ 1;
    __builtin_amdgcn_s_barrier();          // buf[nxt]'s previous MFMA done
    const int c1 = ((it + 1) & 15) * 32;   // wraps harmlessly on last iter
    #pragma unroll
    for (int i = 0; i < 4; i++)
      g2lds16(xsrc + (size_t)(16 * i) * CCH + c1, &xs[nxt][(w * 64 + i * 16) * 32]);
    g2lds16(wsrc + c1, &ws[nxt][w * 16 * 32]);

    S_WAITCNT(5, 15);                      // chunk it landed; it+1 in flight
    __builtin_amdgcn_s_barrier();          // visible to all waves

    #pragma unroll
    for (int ks = 0; ks < 2; ks++) {
      const int cb = ((2 * ks + hi) ^ (ln & 3)) << 3;
      s8v a0 = *(const s8v*)&ws[cur][(ln)           * 32 + cb];
      s8v a1 = *(const s8v*)&ws[cur][(32 + ln)      * 32 + cb];
      s8v b0 = *(const s8v*)&xs[cur][(w * 64 + ln)      * 32 + cb];
      s8v b1 = *(const s8v*)&xs[cur][(w * 64 + 32 + ln) * 32 + cb];
      acc[0] = __builtin_amdgcn_mfma_f32_32x32x16_bf16(a0, b0, acc[0], 0, 0, 0);
      acc[1] = __builtin_amdgcn_mfma_f32_32x32x16_bf16(a0, b1, acc[1], 0, 0, 0);
      acc[2] = __builtin_amdgcn_mfma_f32_32x32x16_bf16(a1, b0, acc[2], 0, 0, 0);
      acc[3] = __builtin_amdgcn_mfma_f32_32x32x16_bf16(a1, b1, acc[3], 0, 0, 0);
    }
  }

  S_WAITCNT(0, 0);                         // drain wrap prefetch
  __builtin_amdgcn_s_barrier();            // all MFMA done before LDS reuse

  if (mt < 8) {
    const int m0g = mt * 64;
    #pragma unroll
    for (int mi = 0; mi < 2; mi++)
      #pragma unroll
      for (int ni = 0; ni < 2; ni++) {
        f16v& a = acc[mi * 2 + ni];
        #pragma unroll
        for (int r = 0; r < 16; r++) {
          int row = (r & 3) + 8 * (r >> 2) + 4 * hi;
          int m   = mi * 32 + row;
          float val = a[r] + bias[m];
          vT[((size_t)b * CCH + m0g + m) * NN + n0 + w * 64 + ni * 32 + ln] = f2bf(val);
        }
      }
  } else {
    // transpose epilogue through swizzled LDS (overlay xs: 32 KB exactly)
    u16* dst = (mt == 8) ? qT : kT;
    u16* xt  = &xs[0][0];                  // [256 rows][64 u16], 8-block xor
    #pragma unroll
    for (int mi = 0; mi < 2; mi++)
      #pragma unroll
      for (int ni = 0; ni < 2; ni++) {
        f16v& a = acc[mi * 2 + ni];
        #pragma unroll
        for (int r = 0; r < 16; r++) {
          int row = (r & 3) + 8 * (r >> 2) + 4 * hi;
          int m   = mi * 32 + row;
          int nr  = w * 64 + ni * 32 + ln;
          xt[(nr << 6) + (((m >> 3) ^ (ln & 7)) << 3) + (m & 7)] = f2bf(a[r] + bias[m]);
        }
      }
    __syncthreads();
    const int r7 = t & 7;
    u16* drow = &dst[((size_t)b * NN + n0 + t) * 64];
    #pragma unroll
    for (int k = 0; k < 8; k++)
      *(uint4*)&drow[k * 8] = *(uint4*)&xt[(t << 6) + ((k ^ r7) << 3)];
  }
}

// ---------------------------------------------------------------------------
// MFMA flash attention v4: V direct-to-register (no vsm), K double-buffered
// in LDS via DMA, P through LDS (transpose). 2 barriers/iter (was 3).
// LDS 32 KB (was 64). V frag is per-lane row-contiguous in vT -> 16B global
// loads, no swizzle needed; L2-resident (4MB slice per slot, slot==bx&7
// keeps each slice on one XCD's L2).
// ---------------------------------------------------------------------------
__global__ __launch_bounds__(256, 2) void attn_kernel(
    const u16* __restrict__ qT,   // [B][N][64] bf16
    const u16* __restrict__ kT,   // [B][N][64] bf16
    const u16* __restrict__ vT,   // [B][C][N] bf16
    const float* __restrict__ x,  // [B][C][N] fp32
    const float* __restrict__ gamma,
    float* __restrict__ out)      // [B][C][N] fp32
{
  __shared__ u16 ksm[2][64 * 64];   // K tiles [j][m], swizzled
  __shared__ u16 plm[2][64 * 64];   // P tiles [q][j], swizzled

  const int bx    = blockIdx.x;
  const int slot  = bx & 7;
  const int b     = slot >> 1;
  const int dbase = (slot & 1) * 256;
  const int i0    = (bx >> 3) * 64;
  const int t     = threadIdx.x;
  const int l     = t & 63, ln = l & 31, hi = l >> 5;
  const int w     = t >> 6;
  const int qh    = w >> 1;
  const int jh    = w & 1;
  const int l3    = l & 7, lh3 = l >> 3;
  const int sw8   = (l3 ^ lh3) * 8;

  s8v qfrag[4];
  {
    const u16* qp = qT + ((size_t)b * NN + i0 + qh * 32 + ln) * 64 + hi * 8;
    #pragma unroll
    for (int k = 0; k < 4; k++) qfrag[k] = *(const s8v*)(qp + 16 * k);
  }

  const u16* kbase = kT + (size_t)b * NN * 64;
  const u16* ksrc  = kbase + (size_t)(16 * w + lh3) * 64 + sw8;
  // per-lane V row pointers: A-frag lane l = V[d = w*32+ln (+128)][j0+(2ks+hi)*8..]
  const u16* vrow0 = vT + ((size_t)b * CCH + dbase + w * 32 + ln) * NN + hi * 8;
  const u16* vrow1 = vrow0 + (size_t)128 * NN;

  f16v oacc[4];                    // [ds][qt]
  #pragma unroll
  for (int i = 0; i < 4; i++)
    #pragma unroll
    for (int r = 0; r < 16; r++) oacc[i][r] = 0.f;
  float lpart[16];
  #pragma unroll
  for (int r = 0; r < 16; r++) lpart[r] = 0.f;

  #pragma unroll
  for (int i = 0; i < 2; i++)
    g2lds16(ksrc + (size_t)(8 * i) * 64, &ksm[0][(w * 2 + i) * 512]);

  for (int it = 0; it < 64; it++) {
    const int j0  = it * 64;
    const int cur = it & 1, nxt = cur ^ 1;

    // V(it) direct to registers; consumed by PV at end of iter (latency
    // hidden under K-wait + QK + softmax).
    s8v vf0[4], vf1[4];
    {
      const u16* vp0 = vrow0 + j0;
      const u16* vp1 = vrow1 + j0;
      #pragma unroll
      for (int ks = 0; ks < 4; ks++) {
        vf0[ks] = *(const s8v*)(vp0 + 16 * ks);
        vf1[ks] = *(const s8v*)(vp1 + 16 * ks);
      }
    }

    // K(it+1) -> ksm[nxt]; safe: last readers of that buffer (QK(it-1))
    // completed before the previous P-barrier.
    const int j1 = ((it + 1) & 63) * 64;
    #pragma unroll
    for (int i = 0; i < 2; i++)
      g2lds16(ksrc + (size_t)(j1 + 8 * i) * 64, &ksm[nxt][(w * 2 + i) * 512]);

    S_WAITCNT(10, 15);                     // K(it) landed (oldest 2); V+K(it+1) in flight
    __builtin_amdgcn_s_barrier();          // B: K(it) visible to all waves

    f16v sacc;
    #pragma unroll
    for (int r = 0; r < 16; r++) sacc[r] = 0.f;
    #pragma unroll
    for (int ks = 0; ks < 4; ks++) {
      s8v bf = *(const s8v*)&ksm[cur][(jh * 32 + ln) * 64 + (((2 * ks + hi) ^ l3) << 3)];
      sacc = __builtin_amdgcn_mfma_f32_32x32x16_bf16(qfrag[ks], bf, sacc, 0, 0, 0);
    }
    #pragma unroll
    for (int r = 0; r < 16; r++) {
      float p = __expf(sacc[r]);
      lpart[r] += p;
      int row = qh * 32 + (r & 3) + ((r >> 2) << 3) + (hi << 2);
      int r7  = (r & 3) + (hi << 2);
      int jbl = (jh << 2) + (ln >> 3);
      plm[cur][(row << 6) + ((jbl ^ r7) << 3) + (ln & 7)] = f2bf(p);
    }

    S_WAITCNT(2, 0);                       // V(it) landed + P flushed; K(it+1) in flight
    __builtin_amdgcn_s_barrier();          // C: P visible

    #pragma unroll
    for (int ks = 0; ks < 4; ks++) {
      const int cb = ((2 * ks + hi) ^ l3) << 3;
      s8v p0 = *(const s8v*)&plm[cur][(ln << 6) + cb];
      s8v p1 = *(const s8v*)&plm[cur][((32 + ln) << 6) + cb];
      oacc[0] = __builtin_amdgcn_mfma_f32_32x32x16_bf16(vf0[ks], p0, oacc[0], 0, 0, 0);
      oacc[1] = __builtin_amdgcn_mfma_f32_32x32x16_bf16(vf0[ks], p1, oacc[1], 0, 0, 0);
      oacc[2] = __builtin_amdgcn_mfma_f32_32x32x16_bf16(vf1[ks], p0, oacc[2], 0, 0, 0);
      oacc[3] = __builtin_amdgcn_mfma_f32_32x32x16_bf16(vf1[ks], p1, oacc[3], 0, 0, 0);
    }
  }

  S_WAITCNT(0, 0);
  __builtin_amdgcn_s_barrier();

  float* lred = (float*)&ksm[0][0];   // [2][64]
  #pragma unroll
  for (int r = 0; r < 16; r++) {
    float v = lpart[r];
    v += __shfl_xor(v, 1);  v += __shfl_xor(v, 2);  v += __shfl_xor(v, 4);
    v += __shfl_xor(v, 8);  v += __shfl_xor(v, 16);
    lpart[r] = v;
  }
  if (ln == 0) {
    #pragma unroll
    for (int r = 0; r < 16; r++) {
      int row = qh * 32 + (r & 3) + ((r >> 2) << 3) + (hi << 2);
      lred[jh * 64 + row] = lpart[r];
    }
  }
  __syncthreads();

  const float g0 = gamma[0];
  #pragma unroll
  for (int qt = 0; qt < 2; qt++) {
    const float linv = 1.0f / (lred[qt * 32 + ln] + lred[64 + qt * 32 + ln]);
    const int n = i0 + qt * 32 + ln;
    #pragma unroll
    for (int ds = 0; ds < 2; ds++) {
      f16v& a = oacc[ds * 2 + qt];
      const int dg = dbase + (w + 4 * ds) * 32;
      #pragma unroll
      for (int r = 0; r < 16; r++) {
        int dl = (r & 3) + 8 * (r >> 2) + 4 * hi;
        size_t idx = ((size_t)b * CCH + dg + dl) * NN + n;
        out[idx] = g0 * a[r] * linv + x[idx];
      }
    }
  }
}

// ---------------------------------------------------------------------------
extern "C" void kernel_launch(void* const* d_in, const int* in_sizes, int n_in,
                              void* d_out, int out_size, void* d_ws, size_t ws_size,
                              hipStream_t stream) {
  const float* x     = (const float*)d_in[0];
  const float* Wq    = (const float*)d_in[1];
  const float* bq    = (const float*)d_in[2];
  const float* Wk    = (const float*)d_in[3];
  const float* bk    = (const float*)d_in[4];
  const float* Wv    = (const float*)d_in[5];
  const float* bv    = (const float*)d_in[6];
  const float* gamma = (const float*)d_in[7];
  float* out = (float*)d_out;

  u16* qT  = (u16*)d_ws;                           // [B][N][64]   2 MB
  u16* kT  = qT  + (size_t)BATCH * NN * MIDD;      // [B][N][64]   2 MB
  u16* vT  = kT  + (size_t)BATCH * NN * MIDD;      // [B][C][N]   16.8 MB
  u16* xbT = vT  + (size_t)BATCH * CCH * NN;       // [B][N][C]   16.8 MB
  u16* Wb  = xbT + (size_t)BATCH * NN * CCH;       // [640][512]   0.66 MB

  prep_w<<<dim3(160), 256, 0, stream>>>(Wq, Wk, Wv, Wb);
  transpose_cast<<<dim3(NN / 64, CCH / 64, BATCH), 256, 0, stream>>>(x, xbT);
  proj_gemm<<<dim3(NN / 256, 10, BATCH), 256, 0, stream>>>(
      xbT, Wb, bq, bk, bv, qT, kT, vT);
  attn_kernel<<<dim3(512), 256, 0, stream>>>(qT, kT, vT, x, gamma, out);
}

// Round 2
// 223.933 us; speedup vs baseline: 1.1491x; 1.1491x over previous
//
#include <hip/hip_runtime.h>

#define BATCH 4
#define CCH   512
#define NN    4096
#define MIDD  64

typedef unsigned short u16;
typedef unsigned int   u32;
typedef short s8v  __attribute__((ext_vector_type(8)));
typedef float f16v __attribute__((ext_vector_type(16)));

__device__ __forceinline__ u16 f2bf(float f) {
  u32 u = __float_as_uint(f);
  u += 0x7fffu + ((u >> 16) & 1u);   // RTNE
  return (u16)(u >> 16);
}

// async global->LDS DMA, 16B per lane; dest = wave-uniform base + lane*16
__device__ __forceinline__ void g2lds16(const u16* g, u16* l) {
  __builtin_amdgcn_global_load_lds(
      (const __attribute__((address_space(1))) u32*)(const void*)g,
      (__attribute__((address_space(3))) u32*)(void*)l, 16, 0, 0);
}

// s_waitcnt imm (gfx9): vmcnt [3:0]+[15:14], expcnt [6:4]=7, lgkmcnt [11:8]
#define S_WAITCNT(vm, lgkm) \
  __builtin_amdgcn_s_waitcnt(((vm) & 15) | (((vm) >> 4) << 14) | (0x7 << 4) | ((lgkm) << 8))

// ---------------------------------------------------------------------------
// prep_w: Wb[640][512] bf16 = [Wq; Wk; Wv] fp32, converted once.
// ---------------------------------------------------------------------------
__global__ __launch_bounds__(256) void prep_w(
    const float* __restrict__ Wq, const float* __restrict__ Wk,
    const float* __restrict__ Wv, u16* __restrict__ Wb)
{
  int e = (blockIdx.x * 256 + threadIdx.x) * 8;
  const float* src;
  if (e < 64 * 512)       src = Wq + e;
  else if (e < 128 * 512) src = Wk + (e - 64 * 512);
  else                    src = Wv + (e - 128 * 512);
  float4 v0 = *(const float4*)src;
  float4 v1 = *(const float4*)(src + 4);
  uint4 p;
  p.x = (u32)f2bf(v0.x) | ((u32)f2bf(v0.y) << 16);
  p.y = (u32)f2bf(v0.z) | ((u32)f2bf(v0.w) << 16);
  p.z = (u32)f2bf(v1.x) | ((u32)f2bf(v1.y) << 16);
  p.w = (u32)f2bf(v1.z) | ((u32)f2bf(v1.w) << 16);
  *(uint4*)(Wb + e) = p;
}

// ---------------------------------------------------------------------------
// transpose_cast: xbT[b][n][c] (bf16) = x[b][c][n] (fp32). 64x64 tiles.
// ---------------------------------------------------------------------------
__global__ __launch_bounds__(256) void transpose_cast(
    const float* __restrict__ x, u16* __restrict__ xbT)
{
  const int b  = blockIdx.z;
  const int c0 = blockIdx.y * 64;
  const int n0 = blockIdx.x * 64;
  const int t  = threadIdx.x;
  __shared__ float ts[64 * 65];

  #pragma unroll
  for (int k = 0; k < 4; k++) {
    int idx = t + 256 * k;
    int cc = idx >> 4, n4 = idx & 15;
    float4 v = *(const float4*)&x[((size_t)(b * CCH + c0 + cc)) * NN + n0 + n4 * 4];
    float* p = &ts[cc * 65 + n4 * 4];
    p[0] = v.x; p[1] = v.y; p[2] = v.z; p[3] = v.w;
  }
  __syncthreads();

  const int n = t >> 2, cb = (t & 3) * 16;
  u16 tmp[16];
  #pragma unroll
  for (int j = 0; j < 16; j++) tmp[j] = f2bf(ts[(cb + j) * 65 + n]);
  u16* dst = &xbT[((size_t)b * NN + n0 + n) * CCH + c0 + cb];
  *(uint4*)&dst[0] = *(uint4*)&tmp[0];
  *(uint4*)&dst[8] = *(uint4*)&tmp[8];
}

// ---------------------------------------------------------------------------
// proj_gemm v4: all-DMA staging, BK=32, double-buffered ws+xs, raw barriers
// with vmcnt(5). V epilogue now writes the fragment-tiled layout
// vF[b][jt][dg][ks][lane][8]: element (d, j) with d = dg*32 + (lane&31),
// j = jt*64 + ks*16 + (lane>>5)*8 + e. Staged through a [64m][256n]
// chunk-XOR-swizzled LDS tile so global stores are 16B / 1KB-per-wave.
// ---------------------------------------------------------------------------
__global__ __launch_bounds__(256, 2) void proj_gemm(
    const u16* __restrict__ xbT, const u16* __restrict__ Wb,
    const float* __restrict__ bq, const float* __restrict__ bk,
    const float* __restrict__ bv,
    u16* __restrict__ qT, u16* __restrict__ kT, u16* __restrict__ vF)
{
  const int b  = blockIdx.z;
  const int mt = blockIdx.y;
  const int n0 = blockIdx.x * 256;
  const int t  = threadIdx.x;
  const int ln = t & 31, hi = (t & 63) >> 5, w = t >> 6;
  const int l  = t & 63;
  const int l2 = l & 3, lr = l >> 2;        // DMA: phys block, row-in-group
  const int swc = (l2 ^ (lr & 3)) * 8;      // content col offset (u16)

  const int mrow0 = (mt < 8) ? (128 + mt * 64) : ((mt == 8) ? 0 : 64);
  const float* bias = (mt < 8) ? (bv + mt * 64) : ((mt == 8) ? bq : bk);

  __shared__ u16 ws[2][64 * 32];    // W chunk [m][c32], swizzled
  __shared__ u16 xs[2][256 * 32];   // x chunk [n][c32], swizzled

  // DMA sources (chunk col offset added per iter)
  const u16* xsrc = xbT + ((size_t)b * NN + n0 + w * 64 + lr) * CCH + swc;
  const u16* wsrc = Wb + (size_t)(mrow0 + w * 16 + lr) * 512 + swc;

  f16v acc[4];
  #pragma unroll
  for (int i = 0; i < 4; i++)
    #pragma unroll
    for (int r = 0; r < 16; r++) acc[i][r] = 0.f;

  // prologue: issue chunk 0 into buf 0
  #pragma unroll
  for (int i = 0; i < 4; i++)
    g2lds16(xsrc + (size_t)(16 * i) * CCH, &xs[0][(w * 64 + i * 16) * 32]);
  g2lds16(wsrc, &ws[0][w * 16 * 32]);

  for (int it = 0; it < 16; it++) {
    const int cur = it & 1, nxt = cur ^ 1;
    __builtin_amdgcn_s_barrier();          // buf[nxt]'s previous MFMA done
    const int c1 = ((it + 1) & 15) * 32;   // wraps harmlessly on last iter
    #pragma unroll
    for (int i = 0; i < 4; i++)
      g2lds16(xsrc + (size_t)(16 * i) * CCH + c1, &xs[nxt][(w * 64 + i * 16) * 32]);
    g2lds16(wsrc + c1, &ws[nxt][w * 16 * 32]);

    S_WAITCNT(5, 15);                      // chunk it landed; it+1 in flight
    __builtin_amdgcn_s_barrier();          // visible to all waves

    #pragma unroll
    for (int ks = 0; ks < 2; ks++) {
      const int cb = ((2 * ks + hi) ^ (ln & 3)) << 3;
      s8v a0 = *(const s8v*)&ws[cur][(ln)           * 32 + cb];
      s8v a1 = *(const s8v*)&ws[cur][(32 + ln)      * 32 + cb];
      s8v b0 = *(const s8v*)&xs[cur][(w * 64 + ln)      * 32 + cb];
      s8v b1 = *(const s8v*)&xs[cur][(w * 64 + 32 + ln) * 32 + cb];
      acc[0] = __builtin_amdgcn_mfma_f32_32x32x16_bf16(a0, b0, acc[0], 0, 0, 0);
      acc[1] = __builtin_amdgcn_mfma_f32_32x32x16_bf16(a0, b1, acc[1], 0, 0, 0);
      acc[2] = __builtin_amdgcn_mfma_f32_32x32x16_bf16(a1, b0, acc[2], 0, 0, 0);
      acc[3] = __builtin_amdgcn_mfma_f32_32x32x16_bf16(a1, b1, acc[3], 0, 0, 0);
    }
  }

  S_WAITCNT(0, 0);                         // drain wrap prefetch
  __builtin_amdgcn_s_barrier();            // all MFMA done before LDS reuse

  if (mt < 8) {
    // V epilogue: stage [64 m][256 n] in LDS (16B-chunk index XOR m&31),
    // then emit fragment-tiled vF with 1KB-per-wave coalesced stores.
    u16* xt = &xs[0][0];                   // 64*256 u16 = 32 KB overlay
    #pragma unroll
    for (int mi = 0; mi < 2; mi++)
      #pragma unroll
      for (int ni = 0; ni < 2; ni++) {
        f16v& a = acc[mi * 2 + ni];
        #pragma unroll
        for (int r = 0; r < 16; r++) {
          int row = (r & 3) + 8 * (r >> 2) + 4 * hi;
          int m   = mi * 32 + row;
          int nr  = w * 64 + ni * 32 + ln;
          int c8  = nr >> 3;
          xt[m * 256 + ((c8 ^ (m & 31)) << 3) + (nr & 7)] = f2bf(a[r] + bias[m]);
        }
      }
    __syncthreads();
    // wave w -> jt_rel = w. Per (mh, ks): lane l supplies vF[...][l][0..7].
    const int jt0 = n0 >> 6;
    const size_t dgb = ((size_t)b * 64 + jt0 + w) * 16 + mt * 2;
    #pragma unroll
    for (int mh = 0; mh < 2; mh++)
      #pragma unroll
      for (int ks = 0; ks < 4; ks++) {
        int c8 = w * 8 + ks * 2 + hi;
        int m  = mh * 32 + ln;
        s8v vv = *(const s8v*)&xt[m * 256 + ((c8 ^ ln) << 3)];
        *(s8v*)&vF[(((dgb + mh) * 4 + ks) * 64 + l) * 8] = vv;
      }
  } else {
    // transpose epilogue through swizzled LDS (overlay xs: 32 KB exactly)
    u16* dst = (mt == 8) ? qT : kT;
    u16* xt  = &xs[0][0];                  // [256 rows][64 u16], 8-block xor
    #pragma unroll
    for (int mi = 0; mi < 2; mi++)
      #pragma unroll
      for (int ni = 0; ni < 2; ni++) {
        f16v& a = acc[mi * 2 + ni];
        #pragma unroll
        for (int r = 0; r < 16; r++) {
          int row = (r & 3) + 8 * (r >> 2) + 4 * hi;
          int m   = mi * 32 + row;
          int nr  = w * 64 + ni * 32 + ln;
          xt[(nr << 6) + (((m >> 3) ^ (ln & 7)) << 3) + (m & 7)] = f2bf(a[r] + bias[m]);
        }
      }
    __syncthreads();
    const int r7 = t & 7;
    u16* drow = &dst[((size_t)b * NN + n0 + t) * 64];
    #pragma unroll
    for (int k = 0; k < 8; k++)
      *(uint4*)&drow[k * 8] = *(uint4*)&xt[(t << 6) + ((k ^ r7) << 3)];
  }
}

// ---------------------------------------------------------------------------
// MFMA flash attention v5: V direct-to-register from fragment-tiled vF
// (each V-load instruction = 64 lanes x 16B = 1KB contiguous), K
// double-buffered in LDS via DMA, P through LDS (transpose). 2 barriers/iter,
// 32 KB LDS. No LDS traffic for V at all.
// ---------------------------------------------------------------------------
__global__ __launch_bounds__(256, 2) void attn_kernel(
    const u16* __restrict__ qT,   // [B][N][64] bf16
    const u16* __restrict__ kT,   // [B][N][64] bf16
    const u16* __restrict__ vF,   // [B][64 jt][16 dg][4 ks][64 l][8 e] bf16
    const float* __restrict__ x,  // [B][C][N] fp32
    const float* __restrict__ gamma,
    float* __restrict__ out)      // [B][C][N] fp32
{
  __shared__ u16 ksm[2][64 * 64];   // K tiles [j][m], swizzled
  __shared__ u16 plm[2][64 * 64];   // P tiles [q][j], swizzled

  const int bx    = blockIdx.x;
  const int slot  = bx & 7;
  const int b     = slot >> 1;
  const int dbase = (slot & 1) * 256;
  const int i0    = (bx >> 3) * 64;
  const int t     = threadIdx.x;
  const int l     = t & 63, ln = l & 31, hi = l >> 5;
  const int w     = t >> 6;
  const int qh    = w >> 1;
  const int jh    = w & 1;
  const int l3    = l & 7, lh3 = l >> 3;
  const int sw8   = (l3 ^ lh3) * 8;

  s8v qfrag[4];
  {
    const u16* qp = qT + ((size_t)b * NN + i0 + qh * 32 + ln) * 64 + hi * 8;
    #pragma unroll
    for (int k = 0; k < 4; k++) qfrag[k] = *(const s8v*)(qp + 16 * k);
  }

  const u16* kbase = kT + (size_t)b * NN * 64;
  const u16* ksrc  = kbase + (size_t)(16 * w + lh3) * 64 + sw8;
  // fragment-tiled V: dg half picked by slot, wave owns dg0 (+4 for vf1)
  const u16* vfb = vF + (size_t)b * (64 * 16 * 4 * 64 * 8);
  const int dg0  = (slot & 1) * 8 + w;

  f16v oacc[4];                    // [ds][qt]
  #pragma unroll
  for (int i = 0; i < 4; i++)
    #pragma unroll
    for (int r = 0; r < 16; r++) oacc[i][r] = 0.f;
  float lpart[16];
  #pragma unroll
  for (int r = 0; r < 16; r++) lpart[r] = 0.f;

  #pragma unroll
  for (int i = 0; i < 2; i++)
    g2lds16(ksrc + (size_t)(8 * i) * 64, &ksm[0][(w * 2 + i) * 512]);

  for (int it = 0; it < 64; it++) {
    const int cur = it & 1, nxt = cur ^ 1;

    // V(it) direct to registers (1KB contiguous per instruction); consumed
    // by PV at end of iter — latency hidden under K-wait + QK + softmax.
    s8v vf0[4], vf1[4];
    {
      const u16* vp0 = vfb + (size_t)(it * 16 + dg0) * (4 * 64 * 8) + l * 8;
      #pragma unroll
      for (int ks = 0; ks < 4; ks++) {
        vf0[ks] = *(const s8v*)(vp0 + ks * (64 * 8));
        vf1[ks] = *(const s8v*)(vp0 + 4 * (4 * 64 * 8) + ks * (64 * 8));
      }
    }

    // K(it+1) -> ksm[nxt]; safe: last readers of that buffer (QK(it-1))
    // completed before the previous P-barrier.
    const int j1 = ((it + 1) & 63) * 64;
    #pragma unroll
    for (int i = 0; i < 2; i++)
      g2lds16(ksrc + (size_t)(j1 + 8 * i) * 64, &ksm[nxt][(w * 2 + i) * 512]);

    S_WAITCNT(10, 15);                     // K(it) landed; V(it)+K(it+1) in flight
    __builtin_amdgcn_s_barrier();          // B: K(it) visible to all waves

    f16v sacc;
    #pragma unroll
    for (int r = 0; r < 16; r++) sacc[r] = 0.f;
    #pragma unroll
    for (int ks = 0; ks < 4; ks++) {
      s8v bf = *(const s8v*)&ksm[cur][(jh * 32 + ln) * 64 + (((2 * ks + hi) ^ l3) << 3)];
      sacc = __builtin_amdgcn_mfma_f32_32x32x16_bf16(qfrag[ks], bf, sacc, 0, 0, 0);
    }
    #pragma unroll
    for (int r = 0; r < 16; r++) {
      float p = __expf(sacc[r]);
      lpart[r] += p;
      int row = qh * 32 + (r & 3) + ((r >> 2) << 3) + (hi << 2);
      int r7  = (r & 3) + (hi << 2);
      int jbl = (jh << 2) + (ln >> 3);
      plm[cur][(row << 6) + ((jbl ^ r7) << 3) + (ln & 7)] = f2bf(p);
    }

    S_WAITCNT(2, 0);                       // V(it) landed + P flushed; K(it+1) in flight
    __builtin_amdgcn_s_barrier();          // C: P visible

    #pragma unroll
    for (int ks = 0; ks < 4; ks++) {
      const int cb = ((2 * ks + hi) ^ l3) << 3;
      s8v p0 = *(const s8v*)&plm[cur][(ln << 6) + cb];
      s8v p1 = *(const s8v*)&plm[cur][((32 + ln) << 6) + cb];
      oacc[0] = __builtin_amdgcn_mfma_f32_32x32x16_bf16(vf0[ks], p0, oacc[0], 0, 0, 0);
      oacc[1] = __builtin_amdgcn_mfma_f32_32x32x16_bf16(vf0[ks], p1, oacc[1], 0, 0, 0);
      oacc[2] = __builtin_amdgcn_mfma_f32_32x32x16_bf16(vf1[ks], p0, oacc[2], 0, 0, 0);
      oacc[3] = __builtin_amdgcn_mfma_f32_32x32x16_bf16(vf1[ks], p1, oacc[3], 0, 0, 0);
    }
  }

  S_WAITCNT(0, 0);
  __builtin_amdgcn_s_barrier();

  float* lred = (float*)&ksm[0][0];   // [2][64]
  #pragma unroll
  for (int r = 0; r < 16; r++) {
    float v = lpart[r];
    v += __shfl_xor(v, 1);  v += __shfl_xor(v, 2);  v += __shfl_xor(v, 4);
    v += __shfl_xor(v, 8);  v += __shfl_xor(v, 16);
    lpart[r] = v;
  }
  if (ln == 0) {
    #pragma unroll
    for (int r = 0; r < 16; r++) {
      int row = qh * 32 + (r & 3) + ((r >> 2) << 3) + (hi << 2);
      lred[jh * 64 + row] = lpart[r];
    }
  }
  __syncthreads();

  const float g0 = gamma[0];
  #pragma unroll
  for (int qt = 0; qt < 2; qt++) {
    const float linv = 1.0f / (lred[qt * 32 + ln] + lred[64 + qt * 32 + ln]);
    const int n = i0 + qt * 32 + ln;
    #pragma unroll
    for (int ds = 0; ds < 2; ds++) {
      f16v& a = oacc[ds * 2 + qt];
      const int dg = dbase + (w + 4 * ds) * 32;
      #pragma unroll
      for (int r = 0; r < 16; r++) {
        int dl = (r & 3) + 8 * (r >> 2) + 4 * hi;
        size_t idx = ((size_t)b * CCH + dg + dl) * NN + n;
        out[idx] = g0 * a[r] * linv + x[idx];
      }
    }
  }
}

// ---------------------------------------------------------------------------
extern "C" void kernel_launch(void* const* d_in, const int* in_sizes, int n_in,
                              void* d_out, int out_size, void* d_ws, size_t ws_size,
                              hipStream_t stream) {
  const float* x     = (const float*)d_in[0];
  const float* Wq    = (const float*)d_in[1];
  const float* bq    = (const float*)d_in[2];
  const float* Wk    = (const float*)d_in[3];
  const float* bk    = (const float*)d_in[4];
  const float* Wv    = (const float*)d_in[5];
  const float* bv    = (const float*)d_in[6];
  const float* gamma = (const float*)d_in[7];
  float* out = (float*)d_out;

  u16* qT  = (u16*)d_ws;                           // [B][N][64]   2 MB
  u16* kT  = qT  + (size_t)BATCH * NN * MIDD;      // [B][N][64]   2 MB
  u16* vF  = kT  + (size_t)BATCH * NN * MIDD;      // [B][64][16][4][64][8] 16.8 MB
  u16* xbT = vF  + (size_t)BATCH * CCH * NN;       // [B][N][C]   16.8 MB
  u16* Wb  = xbT + (size_t)BATCH * NN * CCH;       // [640][512]   0.66 MB

  prep_w<<<dim3(160), 256, 0, stream>>>(Wq, Wk, Wv, Wb);
  transpose_cast<<<dim3(NN / 64, CCH / 64, BATCH), 256, 0, stream>>>(x, xbT);
  proj_gemm<<<dim3(NN / 256, 10, BATCH), 256, 0, stream>>>(
      xbT, Wb, bq, bk, bv, qT, kT, vF);
  attn_kernel<<<dim3(512), 256, 0, stream>>>(qT, kT, vF, x, gamma, out);
}